// Round 9
// baseline (349.914 us; speedup 1.0000x reference)
//
#include <hip/hip_runtime.h>
#include <hip/hip_bf16.h>
#include <stdint.h>

#define DEV static __device__ __forceinline__

typedef __attribute__((ext_vector_type(8))) short bf16x8;
typedef __attribute__((ext_vector_type(4))) float f32x4;
typedef unsigned int u32;

static constexpr int T = 4096;
static constexpr int BATCH = 8;
static constexpr int DM = 1024;            // d_model
static constexpr int M1 = BATCH * T;       // 32768 rows into GEMM1
static constexpr int M2 = BATCH * (T + 1); // 32776 rows into GEMM2
static constexpr int M2P = 257 * 128;      // 32896 padded rows for S (128-tile)
static constexpr int NCH = 64;
static constexpr int CL = T / NCH;
static constexpr int NT = 16;              // K tiles (BK=64, K=1024)

DEV unsigned short f2bf(float f) {
  union { float f; unsigned u; } v; v.f = f;
  unsigned u = v.u;
  return (unsigned short)((u + 0x7fffu + ((u >> 16) & 1u)) >> 16);
}
DEV float bf2f(unsigned short s) {
  union { unsigned u; float f; } v; v.u = ((unsigned)s) << 16;
  return v.f;
}
DEV bf16x8 pack8(float4 a, float4 b) {
  bf16x8 r;
  r[0] = (short)f2bf(a.x); r[1] = (short)f2bf(a.y);
  r[2] = (short)f2bf(a.z); r[3] = (short)f2bf(a.w);
  r[4] = (short)f2bf(b.x); r[5] = (short)f2bf(b.y);
  r[6] = (short)f2bf(b.z); r[7] = (short)f2bf(b.w);
  return r;
}

// async global->LDS, 16B per lane. lds dest wave-uniform; g per-lane.
DEV void gl_lds16(const unsigned short* g, unsigned short* lds) {
  __builtin_amdgcn_global_load_lds(
      (const __attribute__((address_space(1))) u32*)g,
      (__attribute__((address_space(3))) u32*)lds,
      16, 0, 0);
}

// ------------- transpose + convert weights: Wt[n][k] = W[k][n] -------------
__global__ void k_transpose(const float* __restrict__ w0, const float* __restrict__ w1,
                            unsigned short* __restrict__ t0, unsigned short* __restrict__ t1) {
  __shared__ float tile[32][33];
  const float* src = blockIdx.z ? w1 : w0;
  unsigned short* dst = blockIdx.z ? t1 : t0;
  int bx = blockIdx.x * 32;
  int by = blockIdx.y * 32;
  int tx = threadIdx.x & 31, ty = threadIdx.x >> 5;
#pragma unroll
  for (int r = 0; r < 32; r += 8)
    tile[ty + r][tx] = src[(by + ty + r) * DM + bx + tx];
  __syncthreads();
#pragma unroll
  for (int r = 0; r < 32; r += 8)
    dst[(bx + ty + r) * DM + by + tx] = f2bf(tile[tx][ty + r]);
}

// ---------------- bf16 MFMA GEMM: C = A @ Wt^T + bias ----------------
// r8 T3-minimum structure: 128x128 tile, BK=64, 4 waves (2x2), per-wave 64x64,
// double-buffered LDS (64 KiB), ONE __syncthreads drain per K-tile.
// XOR swizzle slot^(row&7); B staged via inverse-swizzled gl_lds.
// MODE 0: A = fp32 with FUSED fp32->bf16 convert (reg-staged A), bf16 out.
// MODE 1: A = bf16 via gl_lds, fp32 out, rows < Mvalid.
template <int MODE>
__global__ __launch_bounds__(256, 2) void k_gemm(const void* __restrict__ Asrc,
                                                 const unsigned short* __restrict__ Bt16,
                                                 const float* __restrict__ bias,
                                                 unsigned short* __restrict__ outb,
                                                 float* __restrict__ outf, int Mvalid) {
  __shared__ unsigned short lds[2][2][128 * 64];  // [buf][op A/B][row*64+k] = 64 KiB

  const int tid = threadIdx.x;
  const int w = tid >> 6, l = tid & 63;
  const int wm = w >> 1, wn = w & 1;   // 2x2 wave grid, per-wave 64x64
  const int lo = l & 15, hi = l >> 4;

  // bijective XCD swizzle (nwg % 8 == 0 for both grids)
  const int nwg = gridDim.x, orig = blockIdx.x;
  const int cpx = nwg >> 3;
  const int wg = (orig & 7) * cpx + (orig >> 3);
  const int bm = wg >> 3, bn = wg & 7;
  const int blockM = bm * 128;
  const int blockN = bn * 128;

  const float* A32 = (const float*)Asrc;
  const unsigned short* A16 = (const unsigned short*)Asrc;

  f32x4 acc[4][4];
#pragma unroll
  for (int m = 0; m < 4; m++)
#pragma unroll
    for (int n = 0; n < 4; n++) acc[m][n] = (f32x4){0.f, 0.f, 0.f, 0.f};

  // ---- B staging (both modes) + A staging (MODE 1): gl_lds, wave w covers
  // rows [w*32, w*32+32) as 4 chunks of 8 rows; lane -> row +(l>>3), global
  // source inverse-swizzled: slot (l&7)^((l>>3)&7) (chunk base %8==0).
  const int ssw = (l & 7) ^ ((l >> 3) & 7);
  const unsigned short* pB[4];
  const unsigned short* pA16[4];
#pragma unroll
  for (int c = 0; c < 4; c++) {
    const int rp = w * 32 + c * 8 + (l >> 3);
    pB[c] = Bt16 + (size_t)(blockN + rp) * DM + ssw * 8;
    if (MODE == 1) pA16[c] = A16 + (size_t)(blockM + rp) * DM + ssw * 8;
  }
  auto stageB = [&](int tt, int buf) {
#pragma unroll
    for (int c = 0; c < 4; c++)
      gl_lds16(pB[c] + (size_t)tt * 64, &lds[buf][1][(w * 32 + c * 8) * 64]);
  };
  auto stageA16 = [&](int tt, int buf) {
#pragma unroll
    for (int c = 0; c < 4; c++)
      gl_lds16(pA16[c] + (size_t)tt * 64, &lds[buf][0][(w * 32 + c * 8) * 64]);
  };

  // ---- A staging MODE 0 (fused convert): thread covers row tid>>1, k-half
  // tid&1 (32 fp32 = 8 float4 loads -> 4 swizzled bf16x8 ds_writes).
  const int arow = tid >> 1;
  const int akh = tid & 1;
  const float* pA32 = A32 + (size_t)(blockM + arow) * DM + akh * 32;
  float4 av[8];
  auto loadA32 = [&](int tt) {
#pragma unroll
    for (int i = 0; i < 8; i++)
      av[i] = *(const float4*)(pA32 + (size_t)tt * 64 + i * 4);
  };
  auto writeA32 = [&](int buf) {
#pragma unroll
    for (int s2 = 0; s2 < 4; s2++) {
      const int s = akh * 4 + s2;
      const int phys = s ^ (arow & 7);
      *(bf16x8*)&lds[buf][0][arow * 64 + phys * 8] = pack8(av[s2 * 2], av[s2 * 2 + 1]);
    }
  };

  // ---- prologue
  if (MODE == 0) {
    loadA32(0);
    writeA32(0);
  } else {
    stageA16(0, 0);
  }
  stageB(0, 0);
  __syncthreads();

  for (int t = 0; t < NT; ++t) {
    const int cur = t & 1;
    const bool hasN = (t + 1 < NT);
    if (hasN) {
      if (MODE == 0) loadA32(t + 1);
      else           stageA16(t + 1, cur ^ 1);
      stageB(t + 1, cur ^ 1);
    }

    const unsigned short* La = lds[cur][0];
    const unsigned short* Lb = lds[cur][1];
    bf16x8 aq[4][2], bq[4][2];
#pragma unroll
    for (int kh = 0; kh < 2; kh++) {
      const int g = kh * 4 + hi;
#pragma unroll
      for (int mf = 0; mf < 4; mf++) {
        const int r = wm * 64 + mf * 16 + lo;
        aq[mf][kh] = *(const bf16x8*)(La + r * 64 + (g ^ (r & 7)) * 8);
      }
#pragma unroll
      for (int nf = 0; nf < 4; nf++) {
        const int r = wn * 64 + nf * 16 + lo;
        bq[nf][kh] = *(const bf16x8*)(Lb + r * 64 + (g ^ (r & 7)) * 8);
      }
    }
#pragma unroll
    for (int kh = 0; kh < 2; kh++)
#pragma unroll
      for (int mf = 0; mf < 4; mf++)
#pragma unroll
        for (int nf = 0; nf < 4; nf++)
          acc[mf][nf] = __builtin_amdgcn_mfma_f32_16x16x32_bf16(
              bq[nf][kh], aq[mf][kh], acc[mf][nf], 0, 0, 0);

    if (MODE == 0 && hasN) writeA32(cur ^ 1);  // loads auto-waited here

    __syncthreads();  // single drain per K-tile
  }

  // epilogue: swapped mfma(B,A) mapping (r7-verified):
  // row = blockM + wm*64 + mf*16 + (l&15); col = blockN + wn*64 + nf*16 + (l>>4)*4 + j
#pragma unroll
  for (int mf = 0; mf < 4; mf++) {
    const int row = blockM + wm * 64 + mf * 16 + lo;
    if (MODE == 1 && row >= Mvalid) continue;
#pragma unroll
    for (int nf = 0; nf < 4; nf++) {
      const int col = blockN + wn * 64 + nf * 16 + hi * 4;
      const float4 bv = *(const float4*)(bias + col);
      if (MODE == 0) {
        ushort4 o;
        o.x = f2bf(acc[mf][nf][0] + bv.x);
        o.y = f2bf(acc[mf][nf][1] + bv.y);
        o.z = f2bf(acc[mf][nf][2] + bv.z);
        o.w = f2bf(acc[mf][nf][3] + bv.w);
        *(ushort4*)(outb + (size_t)row * DM + col) = o;
      } else {
        float4 o;
        o.x = acc[mf][nf][0] + bv.x;
        o.y = acc[mf][nf][1] + bv.y;
        o.z = acc[mf][nf][2] + bv.z;
        o.w = acc[mf][nf][3] + bv.w;
        *(float4*)(outf + (size_t)row * DM + col) = o;
      }
    }
  }
}

// ---------------- scan phase A: per-chunk local (zero-init) end state ----------------
__global__ void k_scan_partial(const unsigned short* __restrict__ proj,
                               const float* __restrict__ logit,
                               const float* __restrict__ z0,
                               float* __restrict__ chunkend) {
  int b = blockIdx.x >> 6, c = blockIdx.x & 63;
  int ch = threadIdx.x;
  float a = 1.f / (1.f + expf(-logit[ch >> 6]));
  int t0 = c * CL;
  const unsigned short* p = proj + (size_t)(b * T + t0) * DM + ch;
  float pprev = (t0 == 0) ? z0[ch] : bf2f(p[-DM]);
  float s = 0.f;
  for (int j = 0; j < CL; j++) {
    float pv = bf2f(p[(size_t)j * DM]);
    s = a * s + (1.f - a) * (pv - pprev);
    pprev = pv;
  }
  chunkend[(b * NCH + c) * DM + ch] = s;
}

// ---------------- scan phase B: serial cross-chunk combine ----------------
__global__ void k_scan_combine(const float* __restrict__ chunkend,
                               const float* __restrict__ logit,
                               const float* __restrict__ v0,
                               float* __restrict__ enter) {
  int b = blockIdx.x;
  int ch = threadIdx.x;
  float a = 1.f / (1.f + expf(-logit[ch >> 6]));
  float a2 = a * a, a4 = a2 * a2, a8 = a4 * a4, a16 = a8 * a8, a32 = a16 * a16;
  float aL = a32 * a32;  // a^64
  float e = v0[ch];
  enter[(b * NCH + 0) * DM + ch] = e;
  for (int c = 1; c < NCH; c++) {
    e = aL * e + chunkend[(b * NCH + c - 1) * DM + ch];
    enter[(b * NCH + c) * DM + ch] = e;
  }
}

// ---------------- scan phase C: final scan, write S (bf16) ----------------
__global__ void k_scan_final(const unsigned short* __restrict__ proj,
                             const float* __restrict__ logit,
                             const float* __restrict__ z0,
                             const float* __restrict__ v0,
                             const float* __restrict__ enter,
                             unsigned short* __restrict__ S) {
  int b = blockIdx.x >> 6, c = blockIdx.x & 63;
  int ch = threadIdx.x;
  float a = 1.f / (1.f + expf(-logit[ch >> 6]));
  int t0 = c * CL;
  const unsigned short* p = proj + (size_t)(b * T + t0) * DM + ch;
  unsigned short* so = S + (size_t)(b * (T + 1) + t0 + 1) * DM + ch;
  float pprev = (t0 == 0) ? z0[ch] : bf2f(p[-DM]);
  float s = enter[(b * NCH + c) * DM + ch];
  if (c == 0) S[(size_t)b * (T + 1) * DM + ch] = f2bf(v0[ch]);
  for (int j = 0; j < CL; j++) {
    float pv = bf2f(p[(size_t)j * DM]);
    s = a * s + (1.f - a) * (pv - pprev);
    pprev = pv;
    so[(size_t)j * DM] = f2bf(s);
  }
}

extern "C" void kernel_launch(void* const* d_in, const int* in_sizes, int n_in,
                              void* d_out, int out_size, void* d_ws, size_t ws_size,
                              hipStream_t stream) {
  const float* inputs = (const float*)d_in[0];
  const float* z0     = (const float*)d_in[1];
  const float* W_in   = (const float*)d_in[2];
  const float* b_in   = (const float*)d_in[3];
  const float* W_out  = (const float*)d_in[4];
  const float* b_out  = (const float*)d_in[5];
  const float* slogit = (const float*)d_in[6];
  const float* v0     = (const float*)d_in[7];
  float* out = (float*)d_out;

  char* ws = (char*)d_ws;
  unsigned short* P16   = (unsigned short*)(ws);                 // 67,108,864 B
  unsigned short* S16   = (unsigned short*)(ws + 67108864);      // 67,371,008 B (32896 rows)
  unsigned short* WTin  = (unsigned short*)(ws + 134479872);     // 2,097,152 B
  unsigned short* WTout = (unsigned short*)(ws + 136577024);     // 2,097,152 B
  float* chunkend       = (float*)(ws + 138674176);              // 2,097,152 B
  float* enter          = (float*)(ws + 140771328);              // 2,097,152 B

  // 1. transpose+convert both weights
  k_transpose<<<dim3(32, 32, 2), 256, 0, stream>>>(W_in, W_out, WTin, WTout);
  // 2. GEMM1 (fused fp32->bf16 A-staging): proj = inputs @ W_in + b_in (bf16 out)
  k_gemm<0><<<dim3((M1 / 128) * 8), 256, 0, stream>>>(inputs, WTin, b_in, P16, nullptr, M1);
  // 3. scan: temporal diff + exponential smoothing
  k_scan_partial<<<dim3(BATCH * NCH), 1024, 0, stream>>>(P16, slogit, z0, chunkend);
  k_scan_combine<<<dim3(BATCH), 1024, 0, stream>>>(chunkend, slogit, v0, enter);
  k_scan_final<<<dim3(BATCH * NCH), 1024, 0, stream>>>(P16, slogit, z0, v0, enter, S16);
  // (k_pad dropped: rows >= M2 of S16 only affect guarded-out rows; reads
  //  stay in-bounds of d_ws; bf16 poison 0xAAAA is finite.)
  // 4. GEMM2: out = S @ W_out + b_out (fp32 out, 32776 valid rows of 32896)
  k_gemm<1><<<dim3((M2P / 128) * 8), 256, 0, stream>>>(S16, WTout, b_out, nullptr, out, M2);
}

// Round 10
// 276.332 us; speedup vs baseline: 1.2663x; 1.2663x over previous
//
#include <hip/hip_runtime.h>
#include <hip/hip_bf16.h>
#include <stdint.h>

#define DEV static __device__ __forceinline__

typedef __attribute__((ext_vector_type(8))) short bf16x8;
typedef __attribute__((ext_vector_type(4))) float f32x4;
typedef unsigned int u32;

static constexpr int T = 4096;
static constexpr int BATCH = 8;
static constexpr int DM = 1024;            // d_model
static constexpr int M1 = BATCH * T;       // 32768 rows into GEMM1
static constexpr int M2 = BATCH * (T + 1); // 32776 rows into GEMM2
static constexpr int M2P = 129 * 256;      // 33024 padded rows for S (256-row tiles)
static constexpr int NCH = 64;
static constexpr int CL = T / NCH;
static constexpr int NT = 32;              // K tiles (BK=32, K=1024)

DEV unsigned short f2bf(float f) {
  union { float f; unsigned u; } v; v.f = f;
  unsigned u = v.u;
  return (unsigned short)((u + 0x7fffu + ((u >> 16) & 1u)) >> 16);
}
DEV float bf2f(unsigned short s) {
  union { unsigned u; float f; } v; v.u = ((unsigned)s) << 16;
  return v.f;
}

// async global->LDS, 16B per lane. lds dest wave-uniform; g per-lane.
DEV void gl_lds16(const unsigned short* g, unsigned short* lds) {
  __builtin_amdgcn_global_load_lds(
      (const __attribute__((address_space(1))) u32*)g,
      (__attribute__((address_space(3))) u32*)lds,
      16, 0, 0);
}

// ---------------- fp32 -> bf16 convert of inputs ----------------
__global__ void k_cvt_x(const float4* __restrict__ x, ushort4* __restrict__ o) {
  int i = blockIdx.x * 256 + threadIdx.x;
  float4 v = x[i];
  ushort4 r;
  r.x = f2bf(v.x); r.y = f2bf(v.y); r.z = f2bf(v.z); r.w = f2bf(v.w);
  o[i] = r;
}

// ------------- transpose + convert weights: Wt[n][k] = W[k][n] -------------
__global__ void k_transpose(const float* __restrict__ w0, const float* __restrict__ w1,
                            unsigned short* __restrict__ t0, unsigned short* __restrict__ t1) {
  __shared__ float tile[32][33];
  const float* src = blockIdx.z ? w1 : w0;
  unsigned short* dst = blockIdx.z ? t1 : t0;
  int bx = blockIdx.x * 32;
  int by = blockIdx.y * 32;
  int tx = threadIdx.x & 31, ty = threadIdx.x >> 5;
#pragma unroll
  for (int r = 0; r < 32; r += 8)
    tile[ty + r][tx] = src[(by + ty + r) * DM + bx + tx];
  __syncthreads();
#pragma unroll
  for (int r = 0; r < 32; r += 8)
    dst[(bx + ty + r) * DM + by + tx] = f2bf(tile[tx][ty + r]);
}

// ---------------- bf16 MFMA GEMM: C = A @ Wt^T + bias ----------------
// r10: TLP-scaled T3-minimum. 256x128 tile, BK=32, 512 threads (8 waves as
// 4M x 2N, per-wave 64x64 = 4x4 frags), double-buffered gl_lds (48 KiB LDS),
// ONE __syncthreads drain per K-tile, 2 blocks/CU -> 4 waves/SIMD (2x r8).
// XOR swizzle phys = g ^ ((row>>1)&3) (2-way = free); inverse-swizzled
// global source slot (l&3)^((l>>3)&3). Swapped-operand MFMA epilogue
// (r7/r8-verified mapping). MODE 0: bf16 out. MODE 1: fp32 out, row guard.
template <int MODE>
__global__ __launch_bounds__(512, 4) void k_gemm(const unsigned short* __restrict__ A16,
                                                 const unsigned short* __restrict__ Bt16,
                                                 const float* __restrict__ bias,
                                                 unsigned short* __restrict__ outb,
                                                 float* __restrict__ outf, int Mvalid) {
  // buf: A [256 rows][32 k] at 0, B [128 rows][32 k] at 8192 elems; 24 KiB/buf
  __shared__ unsigned short lds[2][12288];

  const int tid = threadIdx.x;
  const int w = tid >> 6, l = tid & 63;
  const int wm = w >> 1, wn = w & 1;   // 4M x 2N wave grid, per-wave 64x64
  const int lo = l & 15, hi = l >> 4;

  // bijective XCD swizzle (nwg % 8 == 0: 1024 and 1032)
  const int nwg = gridDim.x, orig = blockIdx.x;
  const int cpx = nwg >> 3;
  const int wg = (orig & 7) * cpx + (orig >> 3);
  const int bm = wg >> 3, bn = wg & 7;
  const int blockM = bm * 256;
  const int blockN = bn * 128;

  f32x4 acc[4][4];
#pragma unroll
  for (int m = 0; m < 4; m++)
#pragma unroll
    for (int n = 0; n < 4; n++) acc[m][n] = (f32x4){0.f, 0.f, 0.f, 0.f};

  // staging: lane -> row chunkbase + (l>>2), phys slot l&3; global source
  // inverse-swizzled: logical granule (l&3) ^ ((l>>3)&3)  [row>>1 & 3 of lane row]
  const int sg = (l & 3) ^ ((l >> 3) & 3);
  const unsigned short* pA[2];
#pragma unroll
  for (int c = 0; c < 2; c++)
    pA[c] = A16 + (size_t)(blockM + w * 32 + c * 16 + (l >> 2)) * DM + sg * 8;
  const unsigned short* pB =
      Bt16 + (size_t)(blockN + w * 16 + (l >> 2)) * DM + sg * 8;

  auto stage = [&](int tt, int buf) {
#pragma unroll
    for (int c = 0; c < 2; c++)
      gl_lds16(pA[c] + (size_t)tt * 32, &lds[buf][(w * 32 + c * 16) * 32]);
    gl_lds16(pB + (size_t)tt * 32, &lds[buf][8192 + (w * 16) * 32]);
  };

  stage(0, 0);
  __syncthreads();

  for (int t = 0; t < NT; ++t) {
    const int cur = t & 1;
    if (t + 1 < NT) stage(t + 1, cur ^ 1);  // issue next-tile loads FIRST

    bf16x8 aq[4], bq[4];
#pragma unroll
    for (int mf = 0; mf < 4; mf++) {
      const int r = wm * 64 + mf * 16 + lo;
      aq[mf] = *(const bf16x8*)(&lds[cur][r * 32 + (hi ^ ((r >> 1) & 3)) * 8]);
    }
#pragma unroll
    for (int nf = 0; nf < 4; nf++) {
      const int r = wn * 64 + nf * 16 + lo;
      bq[nf] = *(const bf16x8*)(&lds[cur][8192 + r * 32 + (hi ^ ((r >> 1) & 3)) * 8]);
    }
#pragma unroll
    for (int mf = 0; mf < 4; mf++)
#pragma unroll
      for (int nf = 0; nf < 4; nf++)
        acc[mf][nf] = __builtin_amdgcn_mfma_f32_16x16x32_bf16(
            bq[nf], aq[mf], acc[mf][nf], 0, 0, 0);

    __syncthreads();  // single drain per K-tile
  }

  // epilogue: swapped mfma(B,A) mapping (r7/r8-verified):
  // row = blockM + wm*64 + mf*16 + (l&15); col = blockN + wn*64 + nf*16 + (l>>4)*4 + j
#pragma unroll
  for (int mf = 0; mf < 4; mf++) {
    const int row = blockM + wm * 64 + mf * 16 + lo;
    if (MODE == 1 && row >= Mvalid) continue;
#pragma unroll
    for (int nf = 0; nf < 4; nf++) {
      const int col = blockN + wn * 64 + nf * 16 + hi * 4;
      const float4 bv = *(const float4*)(bias + col);
      if (MODE == 0) {
        ushort4 o;
        o.x = f2bf(acc[mf][nf][0] + bv.x);
        o.y = f2bf(acc[mf][nf][1] + bv.y);
        o.z = f2bf(acc[mf][nf][2] + bv.z);
        o.w = f2bf(acc[mf][nf][3] + bv.w);
        *(ushort4*)(outb + (size_t)row * DM + col) = o;
      } else {
        float4 o;
        o.x = acc[mf][nf][0] + bv.x;
        o.y = acc[mf][nf][1] + bv.y;
        o.z = acc[mf][nf][2] + bv.z;
        o.w = acc[mf][nf][3] + bv.w;
        *(float4*)(outf + (size_t)row * DM + col) = o;
      }
    }
  }
}

// ---------------- scan phase A: per-chunk local (zero-init) end state ----------------
__global__ void k_scan_partial(const unsigned short* __restrict__ proj,
                               const float* __restrict__ logit,
                               const float* __restrict__ z0,
                               float* __restrict__ chunkend) {
  int b = blockIdx.x >> 6, c = blockIdx.x & 63;
  int ch = threadIdx.x;
  float a = 1.f / (1.f + expf(-logit[ch >> 6]));
  int t0 = c * CL;
  const unsigned short* p = proj + (size_t)(b * T + t0) * DM + ch;
  float pprev = (t0 == 0) ? z0[ch] : bf2f(p[-DM]);
  float s = 0.f;
  for (int j = 0; j < CL; j++) {
    float pv = bf2f(p[(size_t)j * DM]);
    s = a * s + (1.f - a) * (pv - pprev);
    pprev = pv;
  }
  chunkend[(b * NCH + c) * DM + ch] = s;
}

// ---------------- scan phase B: serial cross-chunk combine ----------------
__global__ void k_scan_combine(const float* __restrict__ chunkend,
                               const float* __restrict__ logit,
                               const float* __restrict__ v0,
                               float* __restrict__ enter) {
  int b = blockIdx.x;
  int ch = threadIdx.x;
  float a = 1.f / (1.f + expf(-logit[ch >> 6]));
  float a2 = a * a, a4 = a2 * a2, a8 = a4 * a4, a16 = a8 * a8, a32 = a16 * a16;
  float aL = a32 * a32;  // a^64
  float e = v0[ch];
  enter[(b * NCH + 0) * DM + ch] = e;
  for (int c = 1; c < NCH; c++) {
    e = aL * e + chunkend[(b * NCH + c - 1) * DM + ch];
    enter[(b * NCH + c) * DM + ch] = e;
  }
}

// ---------------- scan phase C: final scan, write S (bf16) ----------------
__global__ void k_scan_final(const unsigned short* __restrict__ proj,
                             const float* __restrict__ logit,
                             const float* __restrict__ z0,
                             const float* __restrict__ v0,
                             const float* __restrict__ enter,
                             unsigned short* __restrict__ S) {
  int b = blockIdx.x >> 6, c = blockIdx.x & 63;
  int ch = threadIdx.x;
  float a = 1.f / (1.f + expf(-logit[ch >> 6]));
  int t0 = c * CL;
  const unsigned short* p = proj + (size_t)(b * T + t0) * DM + ch;
  unsigned short* so = S + (size_t)(b * (T + 1) + t0 + 1) * DM + ch;
  float pprev = (t0 == 0) ? z0[ch] : bf2f(p[-DM]);
  float s = enter[(b * NCH + c) * DM + ch];
  if (c == 0) S[(size_t)b * (T + 1) * DM + ch] = f2bf(v0[ch]);
  for (int j = 0; j < CL; j++) {
    float pv = bf2f(p[(size_t)j * DM]);
    s = a * s + (1.f - a) * (pv - pprev);
    pprev = pv;
    so[(size_t)j * DM] = f2bf(s);
  }
}

extern "C" void kernel_launch(void* const* d_in, const int* in_sizes, int n_in,
                              void* d_out, int out_size, void* d_ws, size_t ws_size,
                              hipStream_t stream) {
  const float* inputs = (const float*)d_in[0];
  const float* z0     = (const float*)d_in[1];
  const float* W_in   = (const float*)d_in[2];
  const float* b_in   = (const float*)d_in[3];
  const float* W_out  = (const float*)d_in[4];
  const float* b_out  = (const float*)d_in[5];
  const float* slogit = (const float*)d_in[6];
  const float* v0     = (const float*)d_in[7];
  float* out = (float*)d_out;

  char* ws = (char*)d_ws;
  unsigned short* X16   = (unsigned short*)(ws);                 // 67,108,864 B
  unsigned short* P16   = (unsigned short*)(ws + 67108864);      // 67,108,864 B
  unsigned short* S16   = (unsigned short*)(ws + 134217728);     // 67,633,152 B (33024 rows)
  unsigned short* WTin  = (unsigned short*)(ws + 201850880);     // 2,097,152 B
  unsigned short* WTout = (unsigned short*)(ws + 203948032);     // 2,097,152 B
  float* chunkend       = (float*)(ws + 206045184);              // 2,097,152 B
  float* enter          = (float*)(ws + 208142336);              // 2,097,152 B

  // 1. convert inputs to bf16
  k_cvt_x<<<32768, 256, 0, stream>>>((const float4*)inputs, (ushort4*)X16);
  // 2. transpose+convert both weights
  k_transpose<<<dim3(32, 32, 2), 256, 0, stream>>>(W_in, W_out, WTin, WTout);
  // 3. GEMM1: proj = inputs @ W_in + b_in (bf16 out), 128x8 = 1024 wgs
  k_gemm<0><<<dim3((M1 / 256) * 8), 512, 0, stream>>>(X16, WTin, b_in, P16, nullptr, M1);
  // 4. scan: temporal diff + exponential smoothing
  k_scan_partial<<<dim3(BATCH * NCH), 1024, 0, stream>>>(P16, slogit, z0, chunkend);
  k_scan_combine<<<dim3(BATCH), 1024, 0, stream>>>(chunkend, slogit, v0, enter);
  k_scan_final<<<dim3(BATCH * NCH), 1024, 0, stream>>>(P16, slogit, z0, v0, enter, S16);
  // (pad rows of S16 are unwritten poison: finite bf16, outputs row-guarded)
  // 5. GEMM2: out = S @ W_out + b_out (fp32 out, 32776 valid of 33024), 129x8 = 1032 wgs
  k_gemm<1><<<dim3((M2P / 256) * 8), 512, 0, stream>>>(S16, WTout, b_out, nullptr, out, M2);
}